// Round 6
// baseline (58.323 us; speedup 1.0000x reference)
//
#include <hip/hip_runtime.h>
#include <hip/hip_bf16.h>

#define G_TOTAL 262144
#define ITERS   4
#define WAVES   2
#define NBLK    4096   // 4096 blocks x 2 waves x 8 graphs x 4 iters = 262144

typedef short s8v __attribute__((ext_vector_type(8)));   // 8 x bf16 fragment
typedef float f4v __attribute__((ext_vector_type(4)));

#define MFMA16(a,b,c) __builtin_amdgcn_mfma_f32_16x16x32_bf16(a,b,c,0,0,0)

__device__ __forceinline__ unsigned short f2bf(float f){
    union { __hip_bfloat16 h; unsigned short u; } cv;
    cv.h = __float2bfloat16(f);          // RNE; compiler pairs into v_cvt_pk_bf16_f32
    return cv.u;
}
__device__ __forceinline__ unsigned int pk2(float a, float b){
    return (unsigned int)f2bf(a) | ((unsigned int)f2bf(b) << 16);
}

union FragU { s8v s; uint4 u; };

// Per-wave LDS arena (10496 B), all accesses wave-local -> ZERO barriers.
//  [0,2304)      wsbW  f32[48][12]  rows (g*6+d); dead after band
//  [2304,2560)   dinvW f32[8][8]    dead after band
//  [0,5120)      h1RW  bf16[64][40] (aliases the 2 above; written agg1 after their reads)
//  [0,512)       rsumW f32[2][64]   (aliases h1RW; written agg2 after L2 reads h1RW)
//  [5120,5888)   bandC bf16[48][8]  slot g*6+d: 6 data + 2 zero; pad-dst rows masked at read
//  [5888,10496)  actTW bf16[32][72] (t1 then t2, transposed [ch][noderow])
#define ARENA 10496

__global__ __launch_bounds__(128, 4)
void gcn_wave(const float* __restrict__ x,
              const float* __restrict__ ew,
              const float* __restrict__ W1,
              const float* __restrict__ b1,
              const float* __restrict__ W2,
              const float* __restrict__ b2,
              const float* __restrict__ Wo,
              const float* __restrict__ bo,
              const float* __restrict__ Wb,
              const float* __restrict__ bb,
              float* __restrict__ out)
{
    __shared__ __align__(16) unsigned char LDS[WAVES*ARENA];   // 20992 B

    const int tid = threadIdx.x;
    const int w   = tid >> 6;      // wave 0..1
    const int l   = tid & 63;
    const int lr  = l & 15;
    const int lq  = l >> 4;

    unsigned char* AR = LDS + w*ARENA;
    float*          wsbW  = (float*)AR;
    float*          dinvW = (float*)(AR + 2304);
    unsigned short* h1RW  = (unsigned short*)AR;
    float*          rsumW = (float*)AR;
    unsigned short* bandC = (unsigned short*)(AR + 5120);
    unsigned short* actTW = (unsigned short*)(AR + 5888);

    // ---- loop-invariant lane constants ----
    const int gB = l >> 3, dB = l & 7;           // band-phase (graph,dst) ownership
    const bool bandOK = (dB < 6);
    const int wrow = (gB*6 + dB)*12;             // wsbW row base (dwords)
    int soff0=0, soff1=0, soff2=0, soff3=0;      // ew scatter offsets (dwords)
    if (l < 60) {
        int so[4];
        #pragma unroll
        for (int e = 0; e < 4; ++e) {
            const int idx = l*4 + e;             // 0..239
            const int g = idx/30, r = idx - g*30;
            const int s = r/5,    v = r - s*5;
            const int d = v + (v >= s);
            so[e] = (g*6 + d)*12 + s;
        }
        soff0=so[0]; soff1=so[1]; soff2=so[2]; soff3=so[3];
    }
    const bool dnOK = (lq == 0) && ((lr & 7) < 6);
    int xoff[4];                                  // x gather offsets (dwords, rel gbW*24)
    {
        const int dn  = lr & 7;
        const int dnc = (dn < 6) ? dn : 0;        // clamp keeps pad lanes in-bounds
        #pragma unroll
        for (int mt = 0; mt < 4; ++mt)
            xoff[mt] = (2*mt + (lr >> 3))*24 + dnc*4;
    }
    const bool aggB  = (lq == (lr >> 3)) && ((lr & 7) < 6);  // band-frag load mask
    const int  boffL = lq*48 + (lr & 7)*8;                   // bandC offset (bf16), + nt*96

    // ---- per-lane weight fragments & scalars (once per block) ----
    s8v w1f[2], w2f[2];
    #pragma unroll
    for (int nt = 0; nt < 2; ++nt) {
        #pragma unroll
        for (int e = 0; e < 8; ++e) {
            const int k = lq*8 + e, col = lr + 16*nt;
            w1f[nt][e] = (k < 4) ? (short)f2bf(W1[k*32 + col]) : (short)0;
            w2f[nt][e] = (short)f2bf(W2[k*32 + col]);
        }
    }
    f4v cb1[2], cb2[2];
    float wor[2][4], wbr[2][4];
    #pragma unroll
    for (int mt = 0; mt < 2; ++mt)
        #pragma unroll
        for (int j = 0; j < 4; ++j) {
            const int ch = 16*mt + lq*4 + j;
            cb1[mt][j] = b1[ch];  cb2[mt][j] = b2[ch];
            wor[mt][j] = Wo[ch];  wbr[mt][j] = Wb[ch];
        }
    const float boS = bo[0], bbS = bb[0];

    const long base = (long)blockIdx.x*(16*ITERS) + w*8;

    // ---- software pipeline: prefetch registers (x pre-packed to bf16) ----
    float4 evB[2];
    uint2  xB[2][4];

    {   // prologue: load iter 0
        const long gb = base;
        if (l < 60) evB[0] = *(const float4*)(ew + gb*30 + l*4);
        if (lq == 0) {
            const float* xp = x + gb*24;
            #pragma unroll
            for (int mt = 0; mt < 4; ++mt) {
                const float4 xv = *(const float4*)(xp + xoff[mt]);
                xB[0][mt] = make_uint2(pk2(xv.x, xv.y), pk2(xv.z, xv.w));
            }
        }
    }

    #pragma unroll
    for (int it = 0; it < ITERS; ++it) {
        const int  cbuf = it & 1, nbuf = cbuf ^ 1;
        const long gbW  = base + it*16;

        // ---- stage ew: scatter current buffer to wsbW rows ----
        if (l < 60) {
            const float4 ev = evB[cbuf];
            wsbW[soff0] = ev.x; wsbW[soff1] = ev.y;
            wsbW[soff2] = ev.z; wsbW[soff3] = ev.w;
        }

        // ---- prefetch next iteration's globals (latency hides under this iter) ----
        if (it + 1 < ITERS) {
            const long gb = gbW + 16;
            if (l < 60) evB[nbuf] = *(const float4*)(ew + gb*30 + l*4);
            if (lq == 0) {
                const float* xp = x + gb*24;
                #pragma unroll
                for (int mt = 0; mt < 4; ++mt) {
                    const float4 xv = *(const float4*)(xp + xoff[mt]);
                    xB[nbuf][mt] = make_uint2(pk2(xv.x, xv.y), pk2(xv.z, xv.w));
                }
            }
        }

        // ---- band phase: normalized adjacency rows ----
        if (bandOK) {
            wsbW[wrow + dB] = 1.0f;                       // self-loop on diagonal
            const float4 r4 = *(const float4*)(wsbW + wrow);
            const float2 r2 = *(const float2*)(wsbW + wrow + 4);
            const float dd = rsqrtf(r4.x+r4.y+r4.z+r4.w+r2.x+r2.y);
            dinvW[gB*8 + dB] = dd;
            const float4 d4 = *(const float4*)(dinvW + gB*8);
            const float2 d2 = *(const float2*)(dinvW + gB*8 + 4);
            const uint4 bw = make_uint4(pk2(dd*r4.x*d4.x, dd*r4.y*d4.y),
                                        pk2(dd*r4.z*d4.z, dd*r4.w*d4.w),
                                        pk2(dd*r2.x*d2.x, dd*r2.y*d2.y), 0u);
            *(uint4*)(bandC + (gB*6 + dB)*8) = bw;
        }

        // ---- L1: t1 = x @ W1 -> actTW [ch][row]  (A-frags straight from registers) ----
        #pragma unroll
        for (int mt = 0; mt < 4; ++mt) {
            s8v a = {0,0,0,0,0,0,0,0};
            if (dnOK) {                                   // feats in k-slots 0..3
                FragU ua; ua.u = make_uint4(xB[cbuf][mt].x, xB[cbuf][mt].y, 0u, 0u);
                a = ua.s;
            }
            #pragma unroll
            for (int nt = 0; nt < 2; ++nt) {
                f4v z = {0.f,0.f,0.f,0.f};
                f4v t = MFMA16(a, w1f[nt], z);
                *(uint2*)(actTW + (16*nt + lr)*72 + 16*mt + 4*lq) =
                    make_uint2(pk2(t[0],t[1]), pk2(t[2],t[3]));
            }
        }

        // ---- agg1: h1 = relu(Ahat*t1 + b1) -> h1RW [row][ch]  (bias in MFMA C) ----
        #pragma unroll
        for (int nt = 0; nt < 4; ++nt) {
            s8v bfr = {0,0,0,0,0,0,0,0};
            if (aggB) {
                FragU ub; ub.u = *(const uint4*)(bandC + nt*96 + boffL);
                bfr = ub.s;
            }
            #pragma unroll
            for (int mtc = 0; mtc < 2; ++mtc) {
                s8v afr = {0,0,0,0,0,0,0,0};
                if (lq < 2) {                             // k>=16 slots have B=0
                    FragU ua;
                    ua.u = *(const uint4*)(actTW + (16*mtc + lr)*72 + 16*nt + 8*lq);
                    afr = ua.s;
                }
                f4v dD = MFMA16(afr, bfr, cb1[mtc]);      // [ch][dst row 16nt+lr]
                const float h0 = fmaxf(dD[0], 0.f);
                const float h1v= fmaxf(dD[1], 0.f);
                const float h2v= fmaxf(dD[2], 0.f);
                const float h3v= fmaxf(dD[3], 0.f);
                *(uint2*)(h1RW + (16*nt + lr)*40 + 16*mtc + 4*lq) =
                    make_uint2(pk2(h0,h1v), pk2(h2v,h3v));
            }
        }

        // ---- L2: t2 = h1 @ W2 -> actTW ----
        #pragma unroll
        for (int mt = 0; mt < 4; ++mt) {
            FragU ua; ua.u = *(const uint4*)(h1RW + (16*mt + lr)*40 + 8*lq);
            const s8v a = ua.s;
            #pragma unroll
            for (int nt = 0; nt < 2; ++nt) {
                f4v z = {0.f,0.f,0.f,0.f};
                f4v t = MFMA16(a, w2f[nt], z);
                *(uint2*)(actTW + (16*nt + lr)*72 + 16*mt + 4*lq) =
                    make_uint2(pk2(t[0],t[1]), pk2(t[2],t[3]));
            }
        }

        // ---- agg2 (bias in C) + relu + head dots + pool ----
        #pragma unroll
        for (int nt = 0; nt < 4; ++nt) {
            s8v bfr = {0,0,0,0,0,0,0,0};
            if (aggB) {
                FragU ub; ub.u = *(const uint4*)(bandC + nt*96 + boffL);
                bfr = ub.s;
            }
            float po = 0.f, pb = 0.f;
            #pragma unroll
            for (int mtc = 0; mtc < 2; ++mtc) {
                s8v afr = {0,0,0,0,0,0,0,0};
                if (lq < 2) {
                    FragU ua;
                    ua.u = *(const uint4*)(actTW + (16*mtc + lr)*72 + 16*nt + 8*lq);
                    afr = ua.s;
                }
                f4v dD = MFMA16(afr, bfr, cb2[mtc]);
                #pragma unroll
                for (int j = 0; j < 4; ++j) {
                    const float h = fmaxf(dD[j], 0.f);
                    po += h * wor[mtc][j];
                    pb += h * wbr[mtc][j];
                }
            }
            po += __shfl_xor(po, 16);  po += __shfl_xor(po, 32);
            pb += __shfl_xor(pb, 16);  pb += __shfl_xor(pb, 32);
            if (lq == 0)      rsumW[16*nt + lr]      = po;   // pad rows never read back
            else if (lq == 1) rsumW[64 + 16*nt + lr] = pb;
        }

        // ---- out: per-wave 8 graphs x 2 heads ----
        if (l < 16) {
            const int head = l >> 3, gl = l & 7;
            const float* rs = rsumW + head*64 + gl*8;
            const float4 a4 = *(const float4*)rs;
            const float2 a2 = *(const float2*)(rs + 4);
            const float s6 = a4.x+a4.y+a4.z+a4.w+a2.x+a2.y;
            const float zz = s6*(1.f/6.f) + (head ? bbS : boS);
            out[(long)head*G_TOTAL + gbW + gl] = 1.f/(1.f + __expf(-zz));
        }
        // no barrier: next iter's staging overwrites only this wave's arena, program order
    }
}

extern "C" void kernel_launch(void* const* d_in, const int* in_sizes, int n_in,
                              void* d_out, int out_size, void* d_ws, size_t ws_size,
                              hipStream_t stream)
{
    const float* x  = (const float*)d_in[0];
    // d_in[1] = edge_index, d_in[3] = batch: static topology, never read
    const float* ew = (const float*)d_in[2];
    const float* W1 = (const float*)d_in[4];
    const float* b1 = (const float*)d_in[5];
    const float* W2 = (const float*)d_in[6];
    const float* b2 = (const float*)d_in[7];
    const float* Wo = (const float*)d_in[8];
    const float* bo = (const float*)d_in[9];
    const float* Wb = (const float*)d_in[10];
    const float* bb = (const float*)d_in[11];
    float* out = (float*)d_out;

    hipLaunchKernelGGL(gcn_wave, dim3(NBLK), dim3(128), 0, stream,
                       x, ew, W1, b1, W2, b2, Wo, bo, Wb, bb, out);
}

// Round 7
// 55.741 us; speedup vs baseline: 1.0463x; 1.0463x over previous
//
#include <hip/hip_runtime.h>
#include <hip/hip_bf16.h>

#define G_TOTAL 262144
#define ITERS   4
#define WAVES   4
#define NBLK    2048   // 2048 blocks x 4 waves x 8 graphs x 4 iters = 262144

typedef short s8v __attribute__((ext_vector_type(8)));   // 8 x bf16 fragment
typedef float f4v __attribute__((ext_vector_type(4)));

#define MFMA16(a,b,c) __builtin_amdgcn_mfma_f32_16x16x32_bf16(a,b,c,0,0,0)

__device__ __forceinline__ unsigned short f2bf(float f){
    union { __hip_bfloat16 h; unsigned short u; } cv;
    cv.h = __float2bfloat16(f);          // RNE; compiler pairs into v_cvt_pk_bf16_f32
    return cv.u;
}
__device__ __forceinline__ unsigned int pk2(float a, float b){
    return (unsigned int)f2bf(a) | ((unsigned int)f2bf(b) << 16);
}

union FragU { s8v s; uint4 u; };

// Per-wave LDS arena (9728 B), all accesses wave-local -> ZERO barriers.
//  [0,5120)      h1RW bf16[64][40]: cols 0..31 = h1 data; cols 32..39 (the 16B "hole"
//                of each 80B row) hold band slot s=(g*6+d) at byte s*80+64.
//                Holes are never touched by h1/L2/rsum ops; slots 0..5 lie in
//                rsumW's [0,512) range but are consumed (agg nt=0) before rsumW
//                writes, per-wave program order.
//  [0,512)       rsumW f32[2][64] (aliases h1RW rows; written agg2 after L2 reads)
//  [5120,9728)   actTW bf16[32][72] (t1 then t2, transposed [ch][noderow])
#define ARENA 9728

__global__ __launch_bounds__(256, 4)
void gcn_wave(const float* __restrict__ x,
              const float* __restrict__ ew,
              const float* __restrict__ W1,
              const float* __restrict__ b1,
              const float* __restrict__ W2,
              const float* __restrict__ b2,
              const float* __restrict__ Wo,
              const float* __restrict__ bo,
              const float* __restrict__ Wb,
              const float* __restrict__ bb,
              float* __restrict__ out)
{
    __shared__ __align__(16) unsigned char LDS[WAVES*ARENA];   // 38912 B

    const int tid = threadIdx.x;
    const int w   = tid >> 6;      // wave 0..3
    const int l   = tid & 63;
    const int lr  = l & 15;
    const int lq  = l >> 4;

    unsigned char* AR = LDS + w*ARENA;
    unsigned short* h1RW  = (unsigned short*)AR;
    float*          rsumW = (float*)AR;
    unsigned short* actTW = (unsigned short*)(AR + 5120);

    // ---- loop-invariant lane constants ----
    const int gB = l >> 3, dB = l & 7;           // band-phase (graph,dst) ownership
    const bool bandOK = (dB < 6);
    const int dBc = bandOK ? dB : 0;
    int eoff0, eoff1, eoff2, eoff3, eoff4, eoff5;  // per-lane ew gather offsets
    {
        int eo[6];
        #pragma unroll
        for (int s = 0; s < 6; ++s)
            eo[s] = (s == dBc) ? gB*30
                               : gB*30 + s*5 + (dBc - (dBc > s ? 1 : 0));
        eoff0=eo[0]; eoff1=eo[1]; eoff2=eo[2]; eoff3=eo[3]; eoff4=eo[4]; eoff5=eo[5];
    }
    const int bstore = (gB*6 + dBc)*40 + 32;     // band slot store addr (bf16 units)
    const bool dnOK = (lq == 0) && ((lr & 7) < 6);
    int xoff[4];                                  // x gather offsets (dwords, rel gbW*24)
    {
        const int dn  = lr & 7;
        const int dnc = (dn < 6) ? dn : 0;        // clamp keeps pad lanes in-bounds
        #pragma unroll
        for (int mt = 0; mt < 4; ++mt)
            xoff[mt] = (2*mt + (lr >> 3))*24 + dnc*4;
    }
    const bool aggB  = (lq == (lr >> 3)) && ((lr & 7) < 6);  // band-frag load mask
    const int  boffL = (lq*6 + (lr & 7))*40 + 32;            // band read addr, + nt*480

    // ---- per-lane weight fragments & scalars (once per block) ----
    s8v w1f[2], w2f[2];
    #pragma unroll
    for (int nt = 0; nt < 2; ++nt) {
        #pragma unroll
        for (int e = 0; e < 8; ++e) {
            const int k = lq*8 + e, col = lr + 16*nt;
            w1f[nt][e] = (k < 4) ? (short)f2bf(W1[k*32 + col]) : (short)0;
            w2f[nt][e] = (short)f2bf(W2[k*32 + col]);
        }
    }
    f4v cb1[2], cb2[2];
    float wor[2][4], wbr[2][4];
    #pragma unroll
    for (int mt = 0; mt < 2; ++mt)
        #pragma unroll
        for (int j = 0; j < 4; ++j) {
            const int ch = 16*mt + lq*4 + j;
            cb1[mt][j] = b1[ch];  cb2[mt][j] = b2[ch];
            wor[mt][j] = Wo[ch];  wbr[mt][j] = Wb[ch];
        }
    const float boS = bo[0], bbS = bb[0];

    const long base = (long)blockIdx.x*(32*ITERS) + w*8;   // wave's first graph

    // ---- software pipeline: prefetch registers ----
    float evl[2][6];           // 6 edge weights of this lane's band row
    uint2 xB[2][4];            // x rows pre-packed to bf16 (lq==0 lanes)

    {   // prologue: load iter 0
        const long gb30 = base*30;
        evl[0][0] = ew[gb30 + eoff0];  evl[0][1] = ew[gb30 + eoff1];
        evl[0][2] = ew[gb30 + eoff2];  evl[0][3] = ew[gb30 + eoff3];
        evl[0][4] = ew[gb30 + eoff4];  evl[0][5] = ew[gb30 + eoff5];
        if (lq == 0) {
            const float* xp = x + base*24;
            #pragma unroll
            for (int mt = 0; mt < 4; ++mt) {
                const float4 xv = *(const float4*)(xp + xoff[mt]);
                xB[0][mt] = make_uint2(pk2(xv.x, xv.y), pk2(xv.z, xv.w));
            }
        }
    }

    #pragma unroll
    for (int it = 0; it < ITERS; ++it) {
        const int  cbuf = it & 1, nbuf = cbuf ^ 1;
        const long gbW  = base + it*32;

        // ---- prefetch next iteration's globals (latency hides under this iter) ----
        if (it + 1 < ITERS) {
            const long gb30 = (gbW + 32)*30;
            evl[nbuf][0] = ew[gb30 + eoff0];  evl[nbuf][1] = ew[gb30 + eoff1];
            evl[nbuf][2] = ew[gb30 + eoff2];  evl[nbuf][3] = ew[gb30 + eoff3];
            evl[nbuf][4] = ew[gb30 + eoff4];  evl[nbuf][5] = ew[gb30 + eoff5];
            if (lq == 0) {
                const float* xp = x + (gbW + 32)*24;
                #pragma unroll
                for (int mt = 0; mt < 4; ++mt) {
                    const float4 xv = *(const float4*)(xp + xoff[mt]);
                    xB[nbuf][mt] = make_uint2(pk2(xv.x, xv.y), pk2(xv.z, xv.w));
                }
            }
        }

        // ---- band phase: all in registers, one LDS store ----
        {
            const float ws0 = (dB==0) ? 1.0f : evl[cbuf][0];
            const float ws1 = (dB==1) ? 1.0f : evl[cbuf][1];
            const float ws2 = (dB==2) ? 1.0f : evl[cbuf][2];
            const float ws3 = (dB==3) ? 1.0f : evl[cbuf][3];
            const float ws4 = (dB==4) ? 1.0f : evl[cbuf][4];
            const float ws5 = (dB==5) ? 1.0f : evl[cbuf][5];
            const float dd  = rsqrtf(ws0+ws1+ws2+ws3+ws4+ws5);
            const int sb = l & 56;                      // gB*8
            const float dv0 = __shfl(dd, sb+0), dv1 = __shfl(dd, sb+1);
            const float dv2 = __shfl(dd, sb+2), dv3 = __shfl(dd, sb+3);
            const float dv4 = __shfl(dd, sb+4), dv5 = __shfl(dd, sb+5);
            if (bandOK) {
                const uint4 bw = make_uint4(pk2(dd*ws0*dv0, dd*ws1*dv1),
                                            pk2(dd*ws2*dv2, dd*ws3*dv3),
                                            pk2(dd*ws4*dv4, dd*ws5*dv5), 0u);
                *(uint4*)(h1RW + bstore) = bw;
            }
        }

        // ---- L1: t1 = x @ W1 -> actTW [ch][row]  (A-frags straight from registers) ----
        #pragma unroll
        for (int mt = 0; mt < 4; ++mt) {
            s8v a = {0,0,0,0,0,0,0,0};
            if (dnOK) {                                   // feats in k-slots 0..3
                FragU ua; ua.u = make_uint4(xB[cbuf][mt].x, xB[cbuf][mt].y, 0u, 0u);
                a = ua.s;
            }
            #pragma unroll
            for (int nt = 0; nt < 2; ++nt) {
                f4v z = {0.f,0.f,0.f,0.f};
                f4v t = MFMA16(a, w1f[nt], z);
                *(uint2*)(actTW + (16*nt + lr)*72 + 16*mt + 4*lq) =
                    make_uint2(pk2(t[0],t[1]), pk2(t[2],t[3]));
            }
        }

        // ---- agg1: h1 = relu(Ahat*t1 + b1) -> h1RW [row][ch]  (bias in MFMA C) ----
        uint4 bfrv[4];
        #pragma unroll
        for (int nt = 0; nt < 4; ++nt) {
            bfrv[nt] = aggB ? *(const uint4*)(h1RW + nt*480 + boffL)
                            : make_uint4(0u,0u,0u,0u);
            FragU ub; ub.u = bfrv[nt];
            #pragma unroll
            for (int mtc = 0; mtc < 2; ++mtc) {
                s8v afr = {0,0,0,0,0,0,0,0};
                if (lq < 2) {                             // k>=16 slots have B=0
                    FragU ua;
                    ua.u = *(const uint4*)(actTW + (16*mtc + lr)*72 + 16*nt + 8*lq);
                    afr = ua.s;
                }
                f4v dD = MFMA16(afr, ub.s, cb1[mtc]);     // [ch][dst row 16nt+lr]
                const float h0 = fmaxf(dD[0], 0.f);
                const float h1v= fmaxf(dD[1], 0.f);
                const float h2v= fmaxf(dD[2], 0.f);
                const float h3v= fmaxf(dD[3], 0.f);
                *(uint2*)(h1RW + (16*nt + lr)*40 + 16*mtc + 4*lq) =
                    make_uint2(pk2(h0,h1v), pk2(h2v,h3v));
            }
        }

        // ---- L2: t2 = h1 @ W2 -> actTW ----
        #pragma unroll
        for (int mt = 0; mt < 4; ++mt) {
            FragU ua; ua.u = *(const uint4*)(h1RW + (16*mt + lr)*40 + 8*lq);
            const s8v a = ua.s;
            #pragma unroll
            for (int nt = 0; nt < 2; ++nt) {
                f4v z = {0.f,0.f,0.f,0.f};
                f4v t = MFMA16(a, w2f[nt], z);
                *(uint2*)(actTW + (16*nt + lr)*72 + 16*mt + 4*lq) =
                    make_uint2(pk2(t[0],t[1]), pk2(t[2],t[3]));
            }
        }

        // ---- agg2 (bias in C, band frags reused from regs) + relu + head dots ----
        #pragma unroll
        for (int nt = 0; nt < 4; ++nt) {
            FragU ub; ub.u = bfrv[nt];
            float po = 0.f, pb = 0.f;
            #pragma unroll
            for (int mtc = 0; mtc < 2; ++mtc) {
                s8v afr = {0,0,0,0,0,0,0,0};
                if (lq < 2) {
                    FragU ua;
                    ua.u = *(const uint4*)(actTW + (16*mtc + lr)*72 + 16*nt + 8*lq);
                    afr = ua.s;
                }
                f4v dD = MFMA16(afr, ub.s, cb2[mtc]);
                #pragma unroll
                for (int j = 0; j < 4; ++j) {
                    const float h = fmaxf(dD[j], 0.f);
                    po += h * wor[mtc][j];
                    pb += h * wbr[mtc][j];
                }
            }
            po += __shfl_xor(po, 16);  po += __shfl_xor(po, 32);
            pb += __shfl_xor(pb, 16);  pb += __shfl_xor(pb, 32);
            if (lq == 0)      rsumW[16*nt + lr]      = po;   // pad rows never read back
            else if (lq == 1) rsumW[64 + 16*nt + lr] = pb;
        }

        // ---- out: per-wave 8 graphs x 2 heads ----
        if (l < 16) {
            const int head = l >> 3, gl = l & 7;
            const float* rs = rsumW + head*64 + gl*8;
            const float4 a4 = *(const float4*)rs;
            const float2 a2 = *(const float2*)(rs + 4);
            const float s6 = a4.x+a4.y+a4.z+a4.w+a2.x+a2.y;
            const float zz = s6*(1.f/6.f) + (head ? bbS : boS);
            out[(long)head*G_TOTAL + gbW + gl] = 1.f/(1.f + __expf(-zz));
        }
        // no barrier: all LDS traffic is wave-local, ordered by program order
    }
}

extern "C" void kernel_launch(void* const* d_in, const int* in_sizes, int n_in,
                              void* d_out, int out_size, void* d_ws, size_t ws_size,
                              hipStream_t stream)
{
    const float* x  = (const float*)d_in[0];
    // d_in[1] = edge_index, d_in[3] = batch: static topology, never read
    const float* ew = (const float*)d_in[2];
    const float* W1 = (const float*)d_in[4];
    const float* b1 = (const float*)d_in[5];
    const float* W2 = (const float*)d_in[6];
    const float* b2 = (const float*)d_in[7];
    const float* Wo = (const float*)d_in[8];
    const float* bo = (const float*)d_in[9];
    const float* Wb = (const float*)d_in[10];
    const float* bb = (const float*)d_in[11];
    float* out = (float*)d_out;

    hipLaunchKernelGGL(gcn_wave, dim3(NBLK), dim3(256), 0, stream,
                       x, ew, W1, b1, W2, b2, Wo, bo, Wb, bb, out);
}